// Round 1
// baseline (822.021 us; speedup 1.0000x reference)
//
#include <hip/hip_runtime.h>
#include <stdint.h>

#define WAVE 64
#define KNN 16
#define LROWS 8
#define HDIM 128
#define CDIM 20
#define HID 64

// ---------------------------------------------------------------------------
// Kernel 1: exact batched KNN (top-16 by (d2 asc, idx asc)), one wave / query.
// batch_index is sorted -> binary-search the query's batch segment.
// Packed key (monotone f32 transform << 32 | idx) reproduces jax.lax.top_k
// tie-breaking exactly.
// ---------------------------------------------------------------------------
__global__ __launch_bounds__(64) void knn_kernel(
    const float* __restrict__ sxyz,
    const int* __restrict__ bidx,
    const int* __restrict__ fidx,
    int* __restrict__ col,
    int N) {
  const int q = blockIdx.x;
  const int lane = threadIdx.x;
  const int fi = fidx[q];
  const float qx = sxyz[3 * fi + 0];
  const float qy = sxyz[3 * fi + 1];
  const float qz = sxyz[3 * fi + 2];
  const int qb = bidx[fi];

  // [lo, hi) = this batch's segment
  int a = 0, b = N;
  while (a < b) { int m = (a + b) >> 1; if (bidx[m] < qb) a = m + 1; else b = m; }
  const int lo = a;
  b = N;
  while (a < b) { int m = (a + b) >> 1; if (bidx[m] <= qb) a = m + 1; else b = m; }
  const int hi = a;

  __shared__ unsigned long long buf[KNN][WAVE];  // per-lane unsorted top-16
  unsigned long long curmax = ~0ull;
  int maxslot = 0;
#pragma unroll
  for (int s = 0; s < KNN; ++s) buf[s][lane] = ~0ull;

  for (int i = lo + lane; i < hi; i += WAVE) {
    float dx = qx - sxyz[3 * i + 0];
    float dy = qy - sxyz[3 * i + 1];
    float dz = qz - sxyz[3 * i + 2];
    float d2 = fmaf(dx, dx, fmaf(dy, dy, dz * dz));
    unsigned u = __float_as_uint(d2);
    u ^= (u >> 31) ? 0xFFFFFFFFu : 0x80000000u;  // monotone total order incl. negatives
    unsigned long long key = (((unsigned long long)u) << 32) | (unsigned)i;
    if (key < curmax) {  // rare after warm-up (~16*ln(128) inserts/lane)
      buf[maxslot][lane] = key;
      curmax = 0ull;
#pragma unroll
      for (int s = 0; s < KNN; ++s) {
        unsigned long long v = buf[s][lane];
        if (v > curmax) { curmax = v; maxslot = s; }
      }
    }
  }
  __syncthreads();

  // merge: 16 rounds of wave-min over the 64x16 candidates. Keys are unique
  // (distinct idx bits) -> exactly one winning lane per round.
  for (int r = 0; r < KNN; ++r) {
    unsigned long long lmin = ~0ull;
    int lslot = 0;
#pragma unroll
    for (int s = 0; s < KNN; ++s) {
      unsigned long long v = buf[s][lane];
      if (v < lmin) { lmin = v; lslot = s; }
    }
    unsigned long long gmin = lmin;
#pragma unroll
    for (int off = 32; off > 0; off >>= 1) {
      unsigned long long o = __shfl_xor(gmin, off, 64);
      gmin = (o < gmin) ? o : gmin;
    }
    if (lmin == gmin && gmin != ~0ull) {
      buf[lslot][lane] = ~0ull;
      col[q * KNN + r] = (int)(unsigned)(gmin & 0xFFFFFFFFull);
    }
  }
}

// ---------------------------------------------------------------------------
// Kernel 2: fused per-query: gathers, edge MLP (10->64->128), cls GEMV
// (20->128), cosine affinities, synchronous-Jacobi auction, mean score.
// One 128-thread block per query. LDS strides 388 / 129 (padded: conflict-free
// & float4-aligned where needed).
// ---------------------------------------------------------------------------
__global__ __launch_bounds__(128) void fused_kernel(
    const float* __restrict__ sxyz,
    const int* __restrict__ fidx,
    const float* __restrict__ gcn,
    const float* __restrict__ leaf,
    const float* __restrict__ W1, const float* __restrict__ b1,
    const float* __restrict__ W2, const float* __restrict__ b2,
    const float* __restrict__ Wl, const float* __restrict__ bl,
    const int* __restrict__ col,
    float* __restrict__ out) {
  const int q = blockIdx.x;
  const int t = threadIdx.x;

  __shared__ float s_leaf[LROWS * 388];    // [8][384] pad->388 (16B aligned rows, l*4 bank offset)
  __shared__ float s_edge[KNN * 129];      // edge_w  [16][128] pad->129
  __shared__ float s_cls[KNN * 129];       // cls_w
  __shared__ float s_featH[KNN * 129];     // feat_j[:, :128]
  __shared__ float s_featC[KNN * CDIM];    // feat_j[:, 128:148]
  __shared__ float s_hidden[KNN * HID];
  __shared__ float s_ew[KNN * 10];
  __shared__ int s_col[KNN];
  __shared__ float s_rna[24];              // 1/max(||leaf row seg||, eps)
  __shared__ float s_rnb[3][KNN];
  __shared__ float s_mat[LROWS * 17];
  __shared__ float s_cost[KNN];
  __shared__ int s_ass[LROWS];
  __shared__ int s_owner[KNN];
  __shared__ int s_bidcol[LROWS];
  __shared__ float s_bidval[LROWS];
  __shared__ int s_done;

  if (t < KNN) s_col[t] = col[q * KNN + t];
  __syncthreads();

  // --- stage leaf_node_all[q] (3072 floats) via float4 ---
  {
    const float4* lp = (const float4*)(leaf + (size_t)q * (LROWS * 3 * HDIM));
    for (int v = t; v < LROWS * 96; v += 128) {
      float4 f = lp[v];
      int l = v / 96, off = (v % 96) * 4;
      *(float4*)&s_leaf[l * 388 + off] = f;
    }
  }
  // --- gather gcnfeat rows ---
  for (int k = 0; k < KNN; ++k)
    s_featH[k * 129 + t] = gcn[(size_t)s_col[k] * 148 + t];
  for (int v = t; v < KNN * CDIM; v += 128) {
    int k = v / CDIM, c = v % CDIM;
    s_featC[v] = gcn[(size_t)s_col[k] * 148 + HDIM + c];
  }
  // --- edge features [xyz_i, xyz_j, diff, dist] ---
  if (t < KNN) {
    int fi = fidx[q];
    float qx = sxyz[3 * fi + 0], qy = sxyz[3 * fi + 1], qz = sxyz[3 * fi + 2];
    int j = s_col[t];
    float jx = sxyz[3 * j + 0], jy = sxyz[3 * j + 1], jz = sxyz[3 * j + 2];
    float dx = qx - jx, dy = qy - jy, dz = qz - jz;
    float dist = sqrtf(dx * dx + dy * dy + dz * dz);
    float* e = &s_ew[t * 10];
    e[0] = qx; e[1] = qy; e[2] = qz;
    e[3] = jx; e[4] = jy; e[5] = jz;
    e[6] = dx; e[7] = dy; e[8] = dz; e[9] = dist;
  }
  __syncthreads();

  // --- MLP layer 1: hidden[k][j] = relu(b1[j] + sum_i ew[k][i]*W1[i][j]) ---
  for (int r = 0; r < 8; ++r) {
    int o = r * 128 + t;        // per wave k is uniform -> s_ew broadcast reads
    int k = o >> 6, j = o & 63;
    float acc = b1[j];
#pragma unroll
    for (int i = 0; i < 10; ++i) acc = fmaf(s_ew[k * 10 + i], W1[i * 64 + j], acc);
    s_hidden[k * 64 + j] = fmaxf(acc, 0.0f);
  }
  __syncthreads();

  // --- MLP layer 2 (t == output channel h), W2 rows coalesced via L1 ---
  for (int k = 0; k < KNN; ++k) {
    float acc = b2[t];
#pragma unroll 8
    for (int j = 0; j < HID; ++j) acc = fmaf(s_hidden[k * 64 + j], W2[j * 128 + t], acc);
    s_edge[k * 129 + t] = acc;
  }
  // --- cls_w = featC @ Wl + bl ---
  for (int k = 0; k < KNN; ++k) {
    float acc = bl[t];
#pragma unroll
    for (int c = 0; c < CDIM; ++c) acc = fmaf(s_featC[k * CDIM + c], Wl[c * 128 + t], acc);
    s_cls[k * 129 + t] = acc;
  }
  __syncthreads();

  // --- 72 norm jobs: 24 leaf segments + 3x16 b-rows ---
  if (t < 72) {
    const float* base;
    if (t < 24) base = &s_leaf[(t / 3) * 388 + (t % 3) * 128];
    else if (t < 40) base = &s_edge[(t - 24) * 129];
    else if (t < 56) base = &s_cls[(t - 40) * 129];
    else base = &s_featH[(t - 56) * 129];
    float ss = 0.f;
    for (int h = 0; h < 128; ++h) ss = fmaf(base[h], base[h], ss);
    float rn = 1.0f / fmaxf(sqrtf(ss), 1e-8f);
    if (t < 24) s_rna[t] = rn;
    else if (t < 40) s_rnb[0][t - 24] = rn;
    else if (t < 56) s_rnb[1][t - 40] = rn;
    else s_rnb[2][t - 56] = rn;
  }
  __syncthreads();

  // --- 128 cosine dots -> mat[l][k] = (m1+m2)/4 + m3/2 ---
  {
    int l = t >> 4, k = t & 15;
    const float* a0 = &s_leaf[l * 388];
    const float* be = &s_edge[k * 129];
    const float* bc = &s_cls[k * 129];
    const float* bf = &s_featH[k * 129];
    float d0 = 0.f, d1 = 0.f, d2 = 0.f;
    for (int h = 0; h < 128; ++h) {
      d0 = fmaf(a0[h], be[h], d0);
      d1 = fmaf(a0[128 + h], bc[h], d1);
      d2 = fmaf(a0[256 + h], bf[h], d2);
    }
    float m = (d0 * s_rna[l * 3 + 0] * s_rnb[0][k] +
               d1 * s_rna[l * 3 + 1] * s_rnb[1][k]) * 0.25f +
              d2 * s_rna[l * 3 + 2] * s_rnb[2][k] * 0.5f;
    s_mat[l * 17 + k] = m;
  }
  if (t < KNN) { s_cost[t] = 0.f; s_owner[t] = -1; }
  if (t < LROWS) s_ass[t] = -1;
  if (t == 0) s_done = 0;
  __syncthreads();

  // --- synchronous Jacobi auction (matches reference semantics exactly):
  // all unassigned rows bid vs the SAME cost vector; per-column max bid wins,
  // lowest-row tie-break; kick previous owner; eps = 1/L = 0.125.
  for (int it = 0; it < 4096; ++it) {
    if (t < LROWS) {
      int bidc = -1; float bidv = 0.f;
      if (s_ass[t] < 0) {
        float v1 = -1e38f, v2 = -1e38f; int c1 = 0;
        for (int c = 0; c < KNN; ++c) {
          float v = s_mat[t * 17 + c] - s_cost[c];
          if (v > v1) { v2 = v1; v1 = v; c1 = c; }  // strict > == top_k low-idx tie-break
          else if (v > v2) { v2 = v; }
        }
        bidc = c1; bidv = v1 - v2 + 0.125f;
      }
      s_bidcol[t] = bidc; s_bidval[t] = bidv;
    }
    __syncthreads();
    if (t < KNN) {
      float high = -1e38f; int hb = -1;
      for (int r = 0; r < LROWS; ++r)
        if (s_bidcol[r] == t) {
          float bv = s_bidval[r];
          if (bv > high) { high = bv; hb = r; }  // lowest-row tie-break (argmax)
        }
      if (hb >= 0) {
        s_cost[t] += high;
        int prev = s_owner[t];               // prev owner was assigned -> never a bidder
        if (prev >= 0) s_ass[prev] = -1;     // kick
        s_ass[hb] = t;                       // hb was unassigned -> no write conflict
        s_owner[t] = hb;
      }
    }
    __syncthreads();
    if (t == 0) {
      int done = 1;
      for (int r = 0; r < LROWS; ++r) done &= (s_ass[r] >= 0);
      s_done = done;
    }
    __syncthreads();
    if (s_done) break;
  }

  if (t == 0) {
    float s = 0.f;
    for (int r = 0; r < LROWS; ++r) s += s_mat[r * 17 + s_ass[r]];
    out[q] = s * 0.125f;
  }
}

// ---------------------------------------------------------------------------
extern "C" void kernel_launch(void* const* d_in, const int* in_sizes, int n_in,
                              void* d_out, int out_size, void* d_ws, size_t ws_size,
                              hipStream_t stream) {
  const float* sxyz = (const float*)d_in[0];   // [N,3]
  const int* bidx  = (const int*)d_in[1];      // [N]
  const int* fidx  = (const int*)d_in[2];      // [Q]
  const float* gcn = (const float*)d_in[3];    // [N,148]
  const float* leaf = (const float*)d_in[4];   // [Q,8,384]
  const float* W1 = (const float*)d_in[5];
  const float* b1 = (const float*)d_in[6];
  const float* W2 = (const float*)d_in[7];
  const float* b2 = (const float*)d_in[8];
  const float* Wl = (const float*)d_in[9];
  const float* bl = (const float*)d_in[10];
  float* out = (float*)d_out;

  const int N = in_sizes[0] / 3;
  const int Q = in_sizes[2];

  int* col = (int*)d_ws;  // Q*16 ints = 512 KB scratch (fully overwritten each call)

  knn_kernel<<<Q, 64, 0, stream>>>(sxyz, bidx, fidx, col, N);
  fused_kernel<<<Q, 128, 0, stream>>>(sxyz, fidx, gcn, leaf, W1, b1, W2, b2,
                                      Wl, bl, col, out);
}

// Round 2
// 486.751 us; speedup vs baseline: 1.6888x; 1.6888x over previous
//
#include <hip/hip_runtime.h>
#include <stdint.h>

#define KNN 16
#define LROWS 8
#define CAP 1024

// ---------------------------------------------------------------------------
// KNN: threshold-filter design. One wave per query.
// Phase 1: per-lane min over 1024-pt subsample -> 16th smallest of 64 lane
//          minima = provable upper bound on true 16th-NN distance.
// Phase 2: full scan, append d2<=thr survivors (~150) to LDS buffer.
// Phase 3: exact top-16 by packed (d2,idx) key (reproduces lax.top_k ties).
// ---------------------------------------------------------------------------
__global__ __launch_bounds__(64) void knn_kernel(
    const float* __restrict__ sxyz,
    const int* __restrict__ bidx,
    const int* __restrict__ fidx,
    int* __restrict__ col, int N) {
  const int q = blockIdx.x;
  const int lane = threadIdx.x;
  const int fi = fidx[q];
  const float qx = sxyz[3 * fi], qy = sxyz[3 * fi + 1], qz = sxyz[3 * fi + 2];
  const int qb = bidx[fi];

  int a = 0, b = N;
  while (a < b) { int m = (a + b) >> 1; if (bidx[m] < qb) a = m + 1; else b = m; }
  const int lo = a;
  b = N;
  while (a < b) { int m = (a + b) >> 1; if (bidx[m] <= qb) a = m + 1; else b = m; }
  const int hi = a;

  // --- phase 1: threshold ---
  float lmin = 3.0e38f;
  for (int j = 0; j < 16; ++j) {
    int i = lo + lane + 64 * j;
    if (i < hi) {
      float dx = qx - sxyz[3 * i], dy = qy - sxyz[3 * i + 1], dz = qz - sxyz[3 * i + 2];
      lmin = fminf(lmin, fmaf(dx, dx, fmaf(dy, dy, dz * dz)));
    }
  }
  float cur = lmin;
  float thr = 3.0e38f;
  for (int r = 0; r < KNN; ++r) {
    float m = cur;
    for (int off = 32; off; off >>= 1) m = fminf(m, __shfl_xor(m, off, 64));
    unsigned long long ball = __ballot(cur == m);
    int win = __ffsll((unsigned long long)ball) - 1;  // lowest lane holding m
    if (lane == win) cur = 3.0e38f;
    thr = m;
  }

  // --- phase 2: collect survivors ---
  __shared__ unsigned long long s_cand[CAP];
  __shared__ int s_cnt;
  if (lane == 0) s_cnt = 0;
  __syncthreads();
  for (int i = lo + lane; i < hi; i += 64) {
    float dx = qx - sxyz[3 * i], dy = qy - sxyz[3 * i + 1], dz = qz - sxyz[3 * i + 2];
    float d2 = fmaf(dx, dx, fmaf(dy, dy, dz * dz));
    if (d2 <= thr) {  // same fma expr as phase 1 -> bitwise-consistent
      int pos = atomicAdd(&s_cnt, 1);
      if (pos < CAP)  // d2>=0 -> raw bits are order-monotone; idx breaks ties low-first
        s_cand[pos] = (((unsigned long long)__float_as_uint(d2)) << 32) | (unsigned)i;
    }
  }
  __syncthreads();
  int M = s_cnt; if (M > CAP) M = CAP;

  // --- phase 3: 16 rounds of exact wave-min extraction (keys unique) ---
  for (int r = 0; r < KNN; ++r) {
    unsigned long long lm = ~0ull; int ls = -1;
    for (int s = lane; s < M; s += 64) {
      unsigned long long v = s_cand[s];
      if (v < lm) { lm = v; ls = s; }
    }
    unsigned long long g = lm;
    for (int off = 32; off; off >>= 1) {
      unsigned long long o = __shfl_xor(g, off, 64);
      if (o < g) g = o;
    }
    if (lm == g && ls >= 0) {
      s_cand[ls] = ~0ull;
      col[q * KNN + r] = (int)(unsigned)(g & 0xffffffffull);
    }
    __syncthreads();
  }
}

// ---------------------------------------------------------------------------
// Fused per-query kernel. 128 threads. LDS ~24 KB -> 6 blocks/CU (12 waves).
// leaf & gathered gcn rows read from global (L1 broadcast); edge/cls staged
// in LDS (needed for the h-transposing dot). Auction: wave 0 only, volatile
// LDS, no barriers (wave-lockstep Jacobi, exact reference tie-breaks).
// ---------------------------------------------------------------------------
__global__ __launch_bounds__(128) void fused_kernel(
    const float* __restrict__ sxyz,
    const int* __restrict__ fidx,
    const float* __restrict__ gcn,
    const float* __restrict__ leaf,
    const float* __restrict__ W1, const float* __restrict__ b1,
    const float* __restrict__ W2, const float* __restrict__ b2,
    const float* __restrict__ Wl, const float* __restrict__ bl,
    const int* __restrict__ col,
    float* __restrict__ out) {
  const int q = blockIdx.x;
  const int t = threadIdx.x;

  __shared__ float s_edge[KNN * 130];          // stride 130: 2-way banks (free), float2-OK
  __shared__ float s_cls[KNN * 130];
  __shared__ __align__(16) float s_hidden[KNN * 68];  // stride 68: 16B rows, 2-way banks
  __shared__ float s_ew[KNN * 12];
  __shared__ float s_featC[KNN * 20];
  __shared__ int s_col[KNN];
  __shared__ float s_rna[24];
  __shared__ float s_rnb[3][KNN];
  __shared__ float s_mat[LROWS * 17];
  __shared__ float s_cost[KNN];
  __shared__ int s_ass[LROWS];
  __shared__ int s_owner[KNN];
  __shared__ int s_bidc[LROWS];
  __shared__ float s_bidv[LROWS];

  if (t < KNN) s_col[t] = col[q * KNN + t];
  __syncthreads();

  // gather class features [16][20]
  for (int v = t; v < KNN * 20; v += 128)
    s_featC[v] = gcn[(size_t)s_col[v / 20] * 148 + 128 + (v % 20)];
  // edge features
  if (t < KNN) {
    int fi = fidx[q];
    float qx = sxyz[3 * fi], qy = sxyz[3 * fi + 1], qz = sxyz[3 * fi + 2];
    int j = s_col[t];
    float jx = sxyz[3 * j], jy = sxyz[3 * j + 1], jz = sxyz[3 * j + 2];
    float dx = qx - jx, dy = qy - jy, dz = qz - jz;
    float dist = sqrtf(dx * dx + dy * dy + dz * dz);
    float* e = &s_ew[t * 12];
    e[0] = qx; e[1] = qy; e[2] = qz;
    e[3] = jx; e[4] = jy; e[5] = jz;
    e[6] = dx; e[7] = dy; e[8] = dz; e[9] = dist;
  }
  __syncthreads();

  // MLP layer 1: hidden[k][j] = relu(b1[j] + ew[k]·W1[:,j])
  for (int r = 0; r < 8; ++r) {
    int o = r * 128 + t;
    int k = o >> 6, j = o & 63;
    float acc = b1[j];
#pragma unroll
    for (int i = 0; i < 10; ++i) acc = fmaf(s_ew[k * 12 + i], W1[i * 64 + j], acc);
    s_hidden[k * 68 + j] = fmaxf(acc, 0.0f);
  }
  __syncthreads();

  // MLP layer 2, register-blocked: t = output channel, 16 k-accumulators.
  // W2 read ONCE per thread (64 loads, coalesced); hidden via broadcast b128.
  float acc[KNN];
#pragma unroll
  for (int k = 0; k < KNN; ++k) acc[k] = b2[t];
  for (int j4 = 0; j4 < 16; ++j4) {
    float w0 = W2[(4 * j4 + 0) * 128 + t];
    float w1 = W2[(4 * j4 + 1) * 128 + t];
    float w2 = W2[(4 * j4 + 2) * 128 + t];
    float w3 = W2[(4 * j4 + 3) * 128 + t];
#pragma unroll
    for (int k = 0; k < KNN; ++k) {
      float4 h = *(const float4*)&s_hidden[k * 68 + 4 * j4];
      acc[k] = fmaf(h.x, w0, acc[k]);
      acc[k] = fmaf(h.y, w1, acc[k]);
      acc[k] = fmaf(h.z, w2, acc[k]);
      acc[k] = fmaf(h.w, w3, acc[k]);
    }
  }
#pragma unroll
  for (int k = 0; k < KNN; ++k) s_edge[k * 130 + t] = acc[k];

  // cls GEMV, register-blocked
#pragma unroll
  for (int k = 0; k < KNN; ++k) acc[k] = bl[t];
  for (int c = 0; c < 20; ++c) {
    float w = Wl[c * 128 + t];
#pragma unroll
    for (int k = 0; k < KNN; ++k) acc[k] = fmaf(s_featC[k * 20 + c], w, acc[k]);
  }
#pragma unroll
  for (int k = 0; k < KNN; ++k) s_cls[k * 130 + t] = acc[k];
  __syncthreads();

  // 72 norm jobs (4 partial sums for ILP)
  if (t < 72) {
    float s0 = 0, s1 = 0, s2 = 0, s3 = 0;
    if (t < 24) {
      const float* p = leaf + (size_t)q * 3072 + (t / 3) * 384 + (t % 3) * 128;
      for (int h = 0; h < 128; h += 4) {
        s0 = fmaf(p[h], p[h], s0); s1 = fmaf(p[h + 1], p[h + 1], s1);
        s2 = fmaf(p[h + 2], p[h + 2], s2); s3 = fmaf(p[h + 3], p[h + 3], s3);
      }
    } else if (t < 40) {
      const float* p = &s_edge[(t - 24) * 130];
      for (int h = 0; h < 128; h += 4) {
        s0 = fmaf(p[h], p[h], s0); s1 = fmaf(p[h + 1], p[h + 1], s1);
        s2 = fmaf(p[h + 2], p[h + 2], s2); s3 = fmaf(p[h + 3], p[h + 3], s3);
      }
    } else if (t < 56) {
      const float* p = &s_cls[(t - 40) * 130];
      for (int h = 0; h < 128; h += 4) {
        s0 = fmaf(p[h], p[h], s0); s1 = fmaf(p[h + 1], p[h + 1], s1);
        s2 = fmaf(p[h + 2], p[h + 2], s2); s3 = fmaf(p[h + 3], p[h + 3], s3);
      }
    } else {
      const float* p = gcn + (size_t)s_col[t - 56] * 148;
      for (int h = 0; h < 128; h += 4) {
        s0 = fmaf(p[h], p[h], s0); s1 = fmaf(p[h + 1], p[h + 1], s1);
        s2 = fmaf(p[h + 2], p[h + 2], s2); s3 = fmaf(p[h + 3], p[h + 3], s3);
      }
    }
    float rn = 1.0f / fmaxf(sqrtf((s0 + s1) + (s2 + s3)), 1e-8f);
    if (t < 24) s_rna[t] = rn;
    else if (t < 40) s_rnb[0][t - 24] = rn;
    else if (t < 56) s_rnb[1][t - 40] = rn;
    else s_rnb[2][t - 56] = rn;
  }
  __syncthreads();

  // 128 cosine dots -> mat
  {
    int l = t >> 4, k = t & 15;
    const float* a0 = leaf + (size_t)q * 3072 + l * 384;      // 16B-aligned
    const float* bf = gcn + (size_t)s_col[k] * 148;           // 16B-aligned
    const float* be = &s_edge[k * 130];
    const float* bc = &s_cls[k * 130];
    float d0 = 0, d1 = 0, d2 = 0;
    for (int h = 0; h < 128; h += 4) {
      float4 va0 = *(const float4*)&a0[h];
      float4 va1 = *(const float4*)&a0[128 + h];
      float4 va2 = *(const float4*)&a0[256 + h];
      float4 vbf = *(const float4*)&bf[h];
      float2 ve0 = *(const float2*)&be[h];
      float2 ve1 = *(const float2*)&be[h + 2];
      float2 vc0 = *(const float2*)&bc[h];
      float2 vc1 = *(const float2*)&bc[h + 2];
      d0 = fmaf(va0.x, ve0.x, d0); d0 = fmaf(va0.y, ve0.y, d0);
      d0 = fmaf(va0.z, ve1.x, d0); d0 = fmaf(va0.w, ve1.y, d0);
      d1 = fmaf(va1.x, vc0.x, d1); d1 = fmaf(va1.y, vc0.y, d1);
      d1 = fmaf(va1.z, vc1.x, d1); d1 = fmaf(va1.w, vc1.y, d1);
      d2 = fmaf(va2.x, vbf.x, d2); d2 = fmaf(va2.y, vbf.y, d2);
      d2 = fmaf(va2.z, vbf.z, d2); d2 = fmaf(va2.w, vbf.w, d2);
    }
    float m = (d0 * s_rna[l * 3 + 0] * s_rnb[0][k] +
               d1 * s_rna[l * 3 + 1] * s_rnb[1][k]) * 0.25f +
              d2 * s_rna[l * 3 + 2] * s_rnb[2][k] * 0.5f;
    s_mat[l * 17 + k] = m;
  }
  __syncthreads();

  if (t >= 64) return;  // wave 1 done; wave 0 runs the auction barrier-free

  float mrow[KNN];
  if (t < LROWS)
#pragma unroll
    for (int c = 0; c < KNN; ++c) mrow[c] = s_mat[t * 17 + c];

  volatile float* vcost = s_cost;
  volatile int* vass = s_ass;
  volatile int* vown = s_owner;
  volatile int* vbidc = s_bidc;
  volatile float* vbidv = s_bidv;
  if (t < KNN) { vcost[t] = 0.f; vown[t] = -1; }
  if (t < LROWS) vass[t] = -1;

  for (int it = 0; it < 4096; ++it) {
    // row (bid) phase — snapshot-Jacobi: reads cost before any update
    if (t < LROWS) {
      int bc_ = -1; float bv_ = 0.f;
      if (vass[t] < 0) {
        float v1 = -3e38f, v2 = -3e38f; int c1 = 0;
        for (int c = 0; c < KNN; ++c) {
          float v = mrow[c] - vcost[c];
          if (v > v1) { v2 = v1; v1 = v; c1 = c; }   // lowest-col tie-break
          else if (v > v2) v2 = v;
        }
        bc_ = c1; bv_ = v1 - v2 + 0.125f;            // eps = 1/L
      }
      vbidc[t] = bc_; vbidv[t] = bv_;
    }
    __builtin_amdgcn_wave_barrier();
    // column phase
    if (t < KNN) {
      float high = -3e38f; int hb = -1;
      for (int r = 0; r < LROWS; ++r)
        if (vbidc[r] == t) {
          float bv = vbidv[r];
          if (bv > high) { high = bv; hb = r; }      // lowest-row tie-break
        }
      if (hb >= 0) {
        vcost[t] = vcost[t] + high;
        int prev = vown[t];
        if (prev >= 0) vass[prev] = -1;              // kick (prev != any hb)
        vass[hb] = t;
        vown[t] = hb;
      }
    }
    __builtin_amdgcn_wave_barrier();
    int assr = (t < LROWS) ? vass[t] : 0;
    if (__ballot(assr >= 0) == ~0ull) break;
  }

  if (t == 0) {
    float s = 0.f;
    for (int r = 0; r < LROWS; ++r) s += s_mat[r * 17 + vass[r]];
    out[q] = s * 0.125f;
  }
}

// ---------------------------------------------------------------------------
extern "C" void kernel_launch(void* const* d_in, const int* in_sizes, int n_in,
                              void* d_out, int out_size, void* d_ws, size_t ws_size,
                              hipStream_t stream) {
  const float* sxyz = (const float*)d_in[0];
  const int* bidx = (const int*)d_in[1];
  const int* fidx = (const int*)d_in[2];
  const float* gcn = (const float*)d_in[3];
  const float* leaf = (const float*)d_in[4];
  const float* W1 = (const float*)d_in[5];
  const float* b1 = (const float*)d_in[6];
  const float* W2 = (const float*)d_in[7];
  const float* b2 = (const float*)d_in[8];
  const float* Wl = (const float*)d_in[9];
  const float* bl = (const float*)d_in[10];
  float* out = (float*)d_out;

  const int N = in_sizes[0] / 3;
  const int Q = in_sizes[2];

  int* col = (int*)d_ws;

  knn_kernel<<<Q, 64, 0, stream>>>(sxyz, bidx, fidx, col, N);
  fused_kernel<<<Q, 128, 0, stream>>>(sxyz, fidx, gcn, leaf, W1, b1, W2, b2,
                                      Wl, bl, col, out);
}